// Round 4
// baseline (95.233 us; speedup 1.0000x reference)
//
#include <hip/hip_runtime.h>
#include <math.h>

#define EPS 1e-8f

typedef short bf16x8 __attribute__((ext_vector_type(8)));
typedef short bf16x4 __attribute__((ext_vector_type(4)));
typedef float f32x4  __attribute__((ext_vector_type(4)));

// fp32 -> bf16 bits, round-to-nearest-even
__device__ __forceinline__ short f2bf(float f) {
    union { float fv; unsigned u; } v; v.fv = f;
    unsigned r = v.u + 0x7fffu + ((v.u >> 16) & 1u);
    return (short)(r >> 16);
}
__device__ __forceinline__ bf16x8 pack8(float4 a, float4 b) {
    bf16x8 p;
    p[0] = f2bf(a.x); p[1] = f2bf(a.y); p[2] = f2bf(a.z); p[3] = f2bf(a.w);
    p[4] = f2bf(b.x); p[5] = f2bf(b.y); p[6] = f2bf(b.z); p[7] = f2bf(b.w);
    return p;
}

// ---------------------------------------------------------------------------
// K1: proj + normalize + fused quaternion-pair expand.
// Tile 16 rows x 64 cols, 4 waves, K=256 staged FULLY in LDS -> ONE barrier.
// grid (64, 4, 2) = 512 blocks -> 2 blocks/CU.
// C/D layout: col = lane&15, row = (lane>>4)*4 + reg.
// ---------------------------------------------------------------------------
__global__ __launch_bounds__(256, 2) void proj_expand_kernel(
    const float* __restrict__ vis, const float* __restrict__ txt,
    const float* __restrict__ Wv, const float* __restrict__ bv,
    const float* __restrict__ Wt, const float* __restrict__ bt,
    short* __restrict__ expq)
{
    const int which = blockIdx.z;
    const float* X    = which ? txt : vis;
    const float* W    = which ? Wt : Wv;
    const float* bias = which ? bt : bv;
    short* Eo = expq + which * 1024 * 1024;

    const int r0 = blockIdx.x * 16;
    const int c0 = blockIdx.y * 64;
    const int t = threadIdx.x, lane = t & 63, wave = t >> 6;
    const int wc = 16 * wave;
    const int mrow = lane & 15, quad = lane >> 4;

    __shared__ __align__(16) short As[16][264];
    __shared__ __align__(16) short Bs[64][264];

    const int srow = t >> 4, skg = t & 15;        // 16 rows x 16 col-groups
    {   // A: 16 rows x 256
        const float* xp = X + (r0 + srow) * 256 + 16 * skg;
        float4 x0 = *(const float4*)xp,       x1 = *(const float4*)(xp + 4);
        float4 x2 = *(const float4*)(xp + 8), x3 = *(const float4*)(xp + 12);
        *(bf16x8*)&As[srow][16 * skg]     = pack8(x0, x1);
        *(bf16x8*)&As[srow][16 * skg + 8] = pack8(x2, x3);
    }
    #pragma unroll
    for (int u = 0; u < 4; ++u) {                 // B: 64 rows x 256
        const float* wp = W + (c0 + srow + 16 * u) * 256 + 16 * skg;
        float4 w0 = *(const float4*)wp,       w1 = *(const float4*)(wp + 4);
        float4 w2 = *(const float4*)(wp + 8), w3 = *(const float4*)(wp + 12);
        *(bf16x8*)&Bs[srow + 16 * u][16 * skg]     = pack8(w0, w1);
        *(bf16x8*)&Bs[srow + 16 * u][16 * skg + 8] = pack8(w2, w3);
    }
    __syncthreads();

    f32x4 acc = {};
    #pragma unroll
    for (int kh = 0; kh < 8; ++kh) {
        bf16x8 a  = *(bf16x8*)&As[mrow][32 * kh + 8 * quad];
        bf16x8 bf = *(bf16x8*)&Bs[wc + mrow][32 * kh + 8 * quad];
        acc = __builtin_amdgcn_mfma_f32_16x16x32_bf16(a, bf, acc, 0, 0, 0);
    }

    const int col  = c0 + wc + mrow;
    const float bb = bias[col];
    const int head = col >> 2;
    const int qbase = lane & ~3;
    #pragma unroll
    for (int reg = 0; reg < 4; ++reg) {
        const int row = r0 + quad * 4 + reg;
        float v = acc[reg] + bb;
        float s = v * v;
        s += __shfl_xor(s, 1, 64);
        s += __shfl_xor(s, 2, 64);
        float q = v * (1.f / (sqrtf(s) + EPS));
        float q0 = __shfl(q, qbase + 0, 64);
        float q1 = __shfl(q, qbase + 1, 64);
        float q2 = __shfl(q, qbase + 2, 64);
        float q3 = __shfl(q, qbase + 3, 64);
        bf16x4 p;
        p[0] = f2bf(q * q0); p[1] = f2bf(q * q1);
        p[2] = f2bf(q * q2); p[3] = f2bf(q * q3);
        *(bf16x4*)(Eo + row * 1024 + head * 16 + (col & 3) * 4) = p;
    }
}

// ---------------------------------------------------------------------------
// K2: E = exp(dot/1024) bf16, E^T, partial row sums rs[row][32].
// Tile 16(n) x 64(m), 4 waves, kt=128 -> 8 steps / 8 barriers, dbuf.
// grid (32, 8, 2) = 512 blocks, 2 blocks/CU (LDS 43.5 KB).
// ---------------------------------------------------------------------------
__global__ __launch_bounds__(256, 2) void logits_kernel(
    const short* __restrict__ expq, short* __restrict__ E,
    short* __restrict__ ET, float* __restrict__ rs)
{
    const int b  = blockIdx.z;
    const int r0 = blockIdx.x * 16;
    const int c0 = blockIdx.y * 64;
    const int t = threadIdx.x, lane = t & 63, wave = t >> 6;
    const int wc = 16 * wave;
    const int mrow = lane & 15, quad = lane >> 4;

    __shared__ __align__(16) short As[2][16][136];
    __shared__ __align__(16) short Bs[2][64][136];

    const short* Ab = expq + (b * 512 + r0) * 1024;
    const short* Bb = expq + (1024 + b * 512 + c0) * 1024;
    const int srow = t >> 4, skg = t & 15;        // 16 rows x 16 groups of 8

    bf16x8 av, bv[4];
    av = *(const bf16x8*)(Ab + srow * 1024 + 8 * skg);
    #pragma unroll
    for (int u = 0; u < 4; ++u)
        bv[u] = *(const bf16x8*)(Bb + (srow + 16 * u) * 1024 + 8 * skg);
    *(bf16x8*)&As[0][srow][8 * skg] = av;
    #pragma unroll
    for (int u = 0; u < 4; ++u)
        *(bf16x8*)&Bs[0][srow + 16 * u][8 * skg] = bv[u];
    __syncthreads();

    f32x4 acc = {};
    #pragma unroll
    for (int i = 0; i < 8; ++i) {
        const int cur = i & 1, nxt = cur ^ 1;
        if (i < 7) {
            const int k0 = (i + 1) * 128;
            av = *(const bf16x8*)(Ab + srow * 1024 + k0 + 8 * skg);
            #pragma unroll
            for (int u = 0; u < 4; ++u)
                bv[u] = *(const bf16x8*)(Bb + (srow + 16 * u) * 1024 + k0 + 8 * skg);
        }
        #pragma unroll
        for (int kh = 0; kh < 4; ++kh) {
            bf16x8 a  = *(bf16x8*)&As[cur][mrow][32 * kh + 8 * quad];
            bf16x8 bf = *(bf16x8*)&Bs[cur][wc + mrow][32 * kh + 8 * quad];
            acc = __builtin_amdgcn_mfma_f32_16x16x32_bf16(a, bf, acc, 0, 0, 0);
        }
        if (i < 7) {
            *(bf16x8*)&As[nxt][srow][8 * skg] = av;
            #pragma unroll
            for (int u = 0; u < 4; ++u)
                *(bf16x8*)&Bs[nxt][srow + 16 * u][8 * skg] = bv[u];
        }
        __syncthreads();
    }

    float e[4];
    bf16x4 pe;
    const int col = c0 + wc + mrow;
    #pragma unroll
    for (int reg = 0; reg < 4; ++reg) {
        e[reg]  = __expf(acc[reg] * (1.f / 1024.f));
        pe[reg] = f2bf(e[reg]);
        E[(b * 512 + r0 + quad * 4 + reg) * 512 + col] = pe[reg];
    }
    // transposed store: 4 consecutive rows -> one bf16x4
    *(bf16x4*)(ET + (b * 512 + col) * 512 + r0 + quad * 4) = pe;
    // partial sums over this wave's 16 cols
    #pragma unroll
    for (int reg = 0; reg < 4; ++reg) {
        float p = e[reg];
        p += __shfl_xor(p, 1, 64);
        p += __shfl_xor(p, 2, 64);
        p += __shfl_xor(p, 4, 64);
        p += __shfl_xor(p, 8, 64);
        if (mrow == 0)
            rs[(b * 512 + r0 + quad * 4 + reg) * 32 + (c0 >> 4) + wave] = p;
    }
}

// ---------------------------------------------------------------------------
// K3: outputs.  A (E / ET) direct from global (fragment layout); B staged
// in LDS (fp32->bf16 transpose), kt=128 -> 4 steps / 4 barriers, dbuf.
// rinv folded into B-staging for which=1, epilogue for which=0.
// Tile 16 x 64(d), K=512.  grid (32, 4, 4) = 512 blocks.
// ---------------------------------------------------------------------------
__global__ __launch_bounds__(256, 2) void out_kernel(
    const float* __restrict__ vis, const float* __restrict__ txt,
    const short* __restrict__ E, const short* __restrict__ ET,
    const float* __restrict__ rs, const float* __restrict__ hptr,
    float* __restrict__ outv, float* __restrict__ outt)
{
    const int z = blockIdx.z;
    const int b = z & 1, which = z >> 1;
    const int r0 = blockIdx.x * 16;
    const int c0 = blockIdx.y * 64;
    const int t = threadIdx.x, lane = t & 63, wave = t >> 6;
    const int wc = 16 * wave;
    const int mrow = lane & 15, quad = lane >> 4;
    const float hv = hptr[0];

    const short* Ab   = (which ? ET : E) + (b * 512 + r0) * 512;
    const float* S    = (which ? vis : txt) + b * 512 * 256;
    const float* base = (which ? txt : vis) + (b * 512 + r0) * 256;
    float*       out  = (which ? outt : outv) + (b * 512 + r0) * 256;

    __shared__ __align__(16) short Bs[2][64][136];
    __shared__ float rinv_s[512];

    const int kk = t >> 1, dg = t & 1;            // B staging: row k, 32-d half

    // issue chunk-0 global loads FIRST (independent of rinv)
    float4 sv[8];
    {
        const float* sp = S + kk * 256 + c0 + 32 * dg;
        #pragma unroll
        for (int j = 0; j < 8; ++j) sv[j] = *(const float4*)(sp + 4 * j);
    }
    bf16x8 a[4];
    #pragma unroll
    for (int kh = 0; kh < 4; ++kh)
        a[kh] = *(const bf16x8*)(Ab + mrow * 512 + 32 * kh + 8 * quad);

    // softmax denominators (overlaps with the loads above)
    if (which == 0) {
        if (t < 16) {
            const float4* p = (const float4*)(rs + (b * 512 + r0 + t) * 32);
            float4 s4 = {0.f, 0.f, 0.f, 0.f};
            #pragma unroll
            for (int i = 0; i < 8; ++i) {
                float4 v = p[i];
                s4.x += v.x; s4.y += v.y; s4.z += v.z; s4.w += v.w;
            }
            rinv_s[t] = 1.f / (s4.x + s4.y + s4.z + s4.w);
        }
    } else {
        #pragma unroll
        for (int u = 0; u < 2; ++u) {
            const int row = t + 256 * u;
            const float4* p = (const float4*)(rs + (b * 512 + row) * 32);
            float4 s4 = {0.f, 0.f, 0.f, 0.f};
            #pragma unroll
            for (int i = 0; i < 8; ++i) {
                float4 v = p[i];
                s4.x += v.x; s4.y += v.y; s4.z += v.z; s4.w += v.w;
            }
            rinv_s[row] = 1.f / (s4.x + s4.y + s4.z + s4.w);
        }
    }
    __syncthreads();                               // rinv_s ready

    {   // write chunk 0
        const float scl = which ? rinv_s[kk] : 1.f;
        #pragma unroll
        for (int j = 0; j < 8; ++j) {
            Bs[0][32 * dg + 4 * j + 0][kk] = f2bf(sv[j].x * scl);
            Bs[0][32 * dg + 4 * j + 1][kk] = f2bf(sv[j].y * scl);
            Bs[0][32 * dg + 4 * j + 2][kk] = f2bf(sv[j].z * scl);
            Bs[0][32 * dg + 4 * j + 3][kk] = f2bf(sv[j].w * scl);
        }
    }
    __syncthreads();

    f32x4 acc = {};
    #pragma unroll
    for (int i = 0; i < 4; ++i) {
        const int cur = i & 1;
        bf16x8 ca[4];
        #pragma unroll
        for (int kh = 0; kh < 4; ++kh) ca[kh] = a[kh];
        if (i < 3) {
            const int k0 = (i + 1) * 128;
            const float* sp = S + (k0 + kk) * 256 + c0 + 32 * dg;
            #pragma unroll
            for (int j = 0; j < 8; ++j) sv[j] = *(const float4*)(sp + 4 * j);
            #pragma unroll
            for (int kh = 0; kh < 4; ++kh)
                a[kh] = *(const bf16x8*)(Ab + mrow * 512 + k0 + 32 * kh + 8 * quad);
        }
        #pragma unroll
        for (int kh = 0; kh < 4; ++kh) {
            bf16x8 bf = *(bf16x8*)&Bs[cur][wc + mrow][32 * kh + 8 * quad];
            acc = __builtin_amdgcn_mfma_f32_16x16x32_bf16(ca[kh], bf, acc, 0, 0, 0);
        }
        if (i < 3) {
            const int k0 = (i + 1) * 128;
            const float scl = which ? rinv_s[k0 + kk] : 1.f;
            #pragma unroll
            for (int j = 0; j < 8; ++j) {
                Bs[cur ^ 1][32 * dg + 4 * j + 0][kk] = f2bf(sv[j].x * scl);
                Bs[cur ^ 1][32 * dg + 4 * j + 1][kk] = f2bf(sv[j].y * scl);
                Bs[cur ^ 1][32 * dg + 4 * j + 2][kk] = f2bf(sv[j].z * scl);
                Bs[cur ^ 1][32 * dg + 4 * j + 3][kk] = f2bf(sv[j].w * scl);
            }
        }
        __syncthreads();
    }

    const int col = c0 + wc + mrow;
    #pragma unroll
    for (int reg = 0; reg < 4; ++reg) {
        const int row = quad * 4 + reg;
        const float scale = which ? hv : hv * rinv_s[row];
        out[row * 256 + col] = fmaf(scale, acc[reg], base[row * 256 + col]);
    }
}

// ---------------------------------------------------------------------------
extern "C" void kernel_launch(void* const* d_in, const int* in_sizes, int n_in,
                              void* d_out, int out_size, void* d_ws, size_t ws_size,
                              hipStream_t stream)
{
    const float* vis = (const float*)d_in[0];
    const float* txt = (const float*)d_in[1];
    const float* Wv  = (const float*)d_in[2];
    const float* bv  = (const float*)d_in[3];
    const float* Wt  = (const float*)d_in[4];
    const float* bt  = (const float*)d_in[5];
    const float* h   = (const float*)d_in[6];

    float* outv = (float*)d_out;                  // 2*512*256
    float* outt = (float*)d_out + 2 * 512 * 256;

    short* expq = (short*)d_ws;                   // 2048 x 1024 bf16 (4 MB)
    short* E    = expq + 2048 * 1024;             // 1024 x 512 bf16 (1 MB)
    short* ET   = E + 1024 * 512;                 // 1024 x 512 bf16 (1 MB)
    float* rs   = (float*)(ET + 1024 * 512);      // 1024 x 32 fp32 (128 KB)

    proj_expand_kernel<<<dim3(64, 4, 2), 256, 0, stream>>>(vis, txt, Wv, bv, Wt, bt, expq);
    logits_kernel<<<dim3(32, 8, 2), 256, 0, stream>>>(expq, E, ET, rs);
    out_kernel<<<dim3(32, 4, 4), 256, 0, stream>>>(vis, txt, E, ET, rs, h, outv, outt);
}

// Round 5
// 92.007 us; speedup vs baseline: 1.0351x; 1.0351x over previous
//
#include <hip/hip_runtime.h>
#include <math.h>

#define EPS 1e-8f

typedef short bf16x8 __attribute__((ext_vector_type(8)));
typedef short bf16x4 __attribute__((ext_vector_type(4)));
typedef float f32x4  __attribute__((ext_vector_type(4)));

// fp32 -> bf16 bits, round-to-nearest-even
__device__ __forceinline__ short f2bf(float f) {
    union { float fv; unsigned u; } v; v.fv = f;
    unsigned r = v.u + 0x7fffu + ((v.u >> 16) & 1u);
    return (short)(r >> 16);
}
__device__ __forceinline__ bf16x8 pack8(float4 a, float4 b) {
    bf16x8 p;
    p[0] = f2bf(a.x); p[1] = f2bf(a.y); p[2] = f2bf(a.z); p[3] = f2bf(a.w);
    p[4] = f2bf(b.x); p[5] = f2bf(b.y); p[6] = f2bf(b.z); p[7] = f2bf(b.w);
    return p;
}

// ---------------------------------------------------------------------------
// K1: proj + normalize + fused quaternion-pair expand.
// Tile 16 rows x 64 cols, 4 waves (wave w -> cols 16w..16w+15), kt=64, K=256.
// grid (64, 4, 2) = 512 blocks -> 2 blocks/CU, 8 waves/CU.
// Double-buffered LDS, ONE barrier per K-step.
// C/D layout: col = lane&15, row = (lane>>4)*4 + reg.
// ---------------------------------------------------------------------------
__global__ __launch_bounds__(256, 2) void proj_expand_kernel(
    const float* __restrict__ vis, const float* __restrict__ txt,
    const float* __restrict__ Wv, const float* __restrict__ bv,
    const float* __restrict__ Wt, const float* __restrict__ bt,
    short* __restrict__ expq)
{
    const int which = blockIdx.z;
    const float* X    = which ? txt : vis;
    const float* W    = which ? Wt : Wv;
    const float* bias = which ? bt : bv;
    short* Eo = expq + which * 1024 * 1024;

    const int r0 = blockIdx.x * 16;
    const int c0 = blockIdx.y * 64;
    const int t = threadIdx.x, lane = t & 63, wave = t >> 6;
    const int wc = 16 * wave;
    const int mrow = lane & 15, quad = lane >> 4;

    __shared__ __align__(16) short As[2][16][72];
    __shared__ __align__(16) short Bs[2][64][72];

    const int srow = t >> 3, skg = t & 7;
    float4 xa, xb, wa0, wb0, wa1, wb1;

    // prologue: load + write tile 0
    if (t < 128) {
        const float* xp = X + (r0 + srow) * 256 + 8 * skg;
        xa = *(const float4*)xp; xb = *(const float4*)(xp + 4);
    }
    {
        const float* wp0 = W + (c0 + srow) * 256 + 8 * skg;
        const float* wp1 = wp0 + 32 * 256;
        wa0 = *(const float4*)wp0; wb0 = *(const float4*)(wp0 + 4);
        wa1 = *(const float4*)wp1; wb1 = *(const float4*)(wp1 + 4);
    }
    if (t < 128) *(bf16x8*)&As[0][srow][8 * skg] = pack8(xa, xb);
    *(bf16x8*)&Bs[0][srow][8 * skg]      = pack8(wa0, wb0);
    *(bf16x8*)&Bs[0][srow + 32][8 * skg] = pack8(wa1, wb1);
    __syncthreads();

    f32x4 acc = {};
    #pragma unroll
    for (int i = 0; i < 4; ++i) {
        const int cur = i & 1, nxt = cur ^ 1;
        if (i < 3) {                         // issue next-tile loads first
            const int k0 = (i + 1) * 64;
            if (t < 128) {
                const float* xp = X + (r0 + srow) * 256 + k0 + 8 * skg;
                xa = *(const float4*)xp; xb = *(const float4*)(xp + 4);
            }
            const float* wp0 = W + (c0 + srow) * 256 + k0 + 8 * skg;
            const float* wp1 = wp0 + 32 * 256;
            wa0 = *(const float4*)wp0; wb0 = *(const float4*)(wp0 + 4);
            wa1 = *(const float4*)wp1; wb1 = *(const float4*)(wp1 + 4);
        }
        #pragma unroll
        for (int kh = 0; kh < 2; ++kh) {
            bf16x8 a  = *(bf16x8*)&As[cur][mrow][32 * kh + 8 * quad];
            bf16x8 bf = *(bf16x8*)&Bs[cur][wc + mrow][32 * kh + 8 * quad];
            acc = __builtin_amdgcn_mfma_f32_16x16x32_bf16(a, bf, acc, 0, 0, 0);
        }
        if (i < 3) {
            if (t < 128) *(bf16x8*)&As[nxt][srow][8 * skg] = pack8(xa, xb);
            *(bf16x8*)&Bs[nxt][srow][8 * skg]      = pack8(wa0, wb0);
            *(bf16x8*)&Bs[nxt][srow + 32][8 * skg] = pack8(wa1, wb1);
        }
        __syncthreads();
    }

    const int col  = c0 + wc + mrow;
    const float bb = bias[col];
    const int head = col >> 2;
    const int qbase = lane & ~3;
    #pragma unroll
    for (int reg = 0; reg < 4; ++reg) {
        const int row = r0 + quad * 4 + reg;
        float v = acc[reg] + bb;
        float s = v * v;
        s += __shfl_xor(s, 1, 64);
        s += __shfl_xor(s, 2, 64);
        float q = v * (1.f / (sqrtf(s) + EPS));
        float q0 = __shfl(q, qbase + 0, 64);
        float q1 = __shfl(q, qbase + 1, 64);
        float q2 = __shfl(q, qbase + 2, 64);
        float q3 = __shfl(q, qbase + 3, 64);
        bf16x4 p;
        p[0] = f2bf(q * q0); p[1] = f2bf(q * q1);
        p[2] = f2bf(q * q2); p[3] = f2bf(q * q3);
        *(bf16x4*)(Eo + row * 1024 + head * 16 + (col & 3) * 4) = p;
    }
}

// ---------------------------------------------------------------------------
// K2: E = exp(dot/1024) bf16, E^T, partial row sums rs[row][32].
// Tile 16(n) x 64(m), 4 waves, kt=64, K=1024.  grid (32, 8, 2) = 512 blocks.
// Double-buffered LDS, one barrier per K-step.
// ---------------------------------------------------------------------------
__global__ __launch_bounds__(256, 2) void logits_kernel(
    const short* __restrict__ expq, short* __restrict__ E,
    short* __restrict__ ET, float* __restrict__ rs)
{
    const int b  = blockIdx.z;
    const int r0 = blockIdx.x * 16;
    const int c0 = blockIdx.y * 64;
    const int t = threadIdx.x, lane = t & 63, wave = t >> 6;
    const int wc = 16 * wave;
    const int mrow = lane & 15, quad = lane >> 4;

    __shared__ __align__(16) short As[2][16][72];
    __shared__ __align__(16) short Bs[2][64][72];

    const short* Ab = expq + (b * 512 + r0) * 1024;
    const short* Bb = expq + (1024 + b * 512 + c0) * 1024;
    const int srow = t >> 3, skg = t & 7;

    bf16x8 av, b0v, b1v;
    if (t < 128) av = *(const bf16x8*)(Ab + srow * 1024 + 8 * skg);
    b0v = *(const bf16x8*)(Bb + srow * 1024 + 8 * skg);
    b1v = *(const bf16x8*)(Bb + (srow + 32) * 1024 + 8 * skg);
    if (t < 128) *(bf16x8*)&As[0][srow][8 * skg] = av;
    *(bf16x8*)&Bs[0][srow][8 * skg]      = b0v;
    *(bf16x8*)&Bs[0][srow + 32][8 * skg] = b1v;
    __syncthreads();

    f32x4 acc = {};
    #pragma unroll
    for (int i = 0; i < 16; ++i) {
        const int cur = i & 1, nxt = cur ^ 1;
        if (i < 15) {
            const int k0 = (i + 1) * 64;
            if (t < 128) av = *(const bf16x8*)(Ab + srow * 1024 + k0 + 8 * skg);
            b0v = *(const bf16x8*)(Bb + srow * 1024 + k0 + 8 * skg);
            b1v = *(const bf16x8*)(Bb + (srow + 32) * 1024 + k0 + 8 * skg);
        }
        #pragma unroll
        for (int kh = 0; kh < 2; ++kh) {
            bf16x8 a  = *(bf16x8*)&As[cur][mrow][32 * kh + 8 * quad];
            bf16x8 bf = *(bf16x8*)&Bs[cur][wc + mrow][32 * kh + 8 * quad];
            acc = __builtin_amdgcn_mfma_f32_16x16x32_bf16(a, bf, acc, 0, 0, 0);
        }
        if (i < 15) {
            if (t < 128) *(bf16x8*)&As[nxt][srow][8 * skg] = av;
            *(bf16x8*)&Bs[nxt][srow][8 * skg]      = b0v;
            *(bf16x8*)&Bs[nxt][srow + 32][8 * skg] = b1v;
        }
        __syncthreads();
    }

    float e[4];
    bf16x4 pe;
    const int col = c0 + wc + mrow;
    #pragma unroll
    for (int reg = 0; reg < 4; ++reg) {
        e[reg]  = __expf(acc[reg] * (1.f / 1024.f));
        pe[reg] = f2bf(e[reg]);
        E[(b * 512 + r0 + quad * 4 + reg) * 512 + col] = pe[reg];
    }
    // transposed store: 4 consecutive rows -> one bf16x4
    *(bf16x4*)(ET + (b * 512 + col) * 512 + r0 + quad * 4) = pe;
    // partial sums over this wave's 16 cols
    #pragma unroll
    for (int reg = 0; reg < 4; ++reg) {
        float p = e[reg];
        p += __shfl_xor(p, 1, 64);
        p += __shfl_xor(p, 2, 64);
        p += __shfl_xor(p, 4, 64);
        p += __shfl_xor(p, 8, 64);
        if (mrow == 0)
            rs[(b * 512 + r0 + quad * 4 + reg) * 32 + (c0 >> 4) + wave] = p;
    }
}

// ---------------------------------------------------------------------------
// K3: outputs.  A-operands (E / ET) loaded DIRECT from global (fragment
// layout); only B (features, fp32->bf16 transpose) staged in LDS (dbuf,
// one barrier/step).  rinv folded into B-staging for which=1, epilogue for
// which=0.  Tile 16 x 64(d), kt=64, K=512.  grid (32, 4, 4) = 512 blocks.
// ---------------------------------------------------------------------------
__global__ __launch_bounds__(256, 2) void out_kernel(
    const float* __restrict__ vis, const float* __restrict__ txt,
    const short* __restrict__ E, const short* __restrict__ ET,
    const float* __restrict__ rs, const float* __restrict__ hptr,
    float* __restrict__ outv, float* __restrict__ outt)
{
    const int z = blockIdx.z;
    const int b = z & 1, which = z >> 1;
    const int r0 = blockIdx.x * 16;
    const int c0 = blockIdx.y * 64;
    const int t = threadIdx.x, lane = t & 63, wave = t >> 6;
    const int wc = 16 * wave;
    const int mrow = lane & 15, quad = lane >> 4;
    const float hv = hptr[0];

    const short* Ab   = (which ? ET : E) + (b * 512 + r0) * 512;
    const float* S    = (which ? vis : txt) + b * 512 * 256;
    const float* base = (which ? txt : vis) + (b * 512 + r0) * 256;
    float*       out  = (which ? outt : outv) + (b * 512 + r0) * 256;

    __shared__ __align__(16) short Bs[2][64][72];
    __shared__ float rinv_s[512];

    // prologue: softmax denominators
    if (which == 0) {
        if (t < 16) {
            const float* p = rs + (b * 512 + r0 + t) * 32;
            float s = 0.f;
            #pragma unroll
            for (int i = 0; i < 32; ++i) s += p[i];
            rinv_s[t] = 1.f / s;                  // local 16 rows
        }
    } else {
        #pragma unroll
        for (int u = 0; u < 2; ++u) {
            const int row = t + 256 * u;
            const float* p = rs + (b * 512 + row) * 32;
            float s = 0.f;
            #pragma unroll
            for (int i = 0; i < 32; ++i) s += p[i];
            rinv_s[row] = 1.f / s;                // full table (per-k scale)
        }
    }
    __syncthreads();

    const int kk = t >> 2, dg = t & 3;            // B staging coords
    float4 sv0, sv1, sv2, sv3;
    bf16x8 a0, a1;

    // prologue: load + write tile 0
    {
        const float* sp = S + kk * 256 + c0 + 16 * dg;
        sv0 = *(const float4*)sp;      sv1 = *(const float4*)(sp + 4);
        sv2 = *(const float4*)(sp + 8); sv3 = *(const float4*)(sp + 12);
        a0 = *(const bf16x8*)(Ab + mrow * 512 + 8 * quad);
        a1 = *(const bf16x8*)(Ab + mrow * 512 + 32 + 8 * quad);
        const float scl = which ? rinv_s[kk] : 1.f;
        const float f[16] = { sv0.x, sv0.y, sv0.z, sv0.w, sv1.x, sv1.y, sv1.z, sv1.w,
                              sv2.x, sv2.y, sv2.z, sv2.w, sv3.x, sv3.y, sv3.z, sv3.w };
        #pragma unroll
        for (int i = 0; i < 16; ++i) Bs[0][16 * dg + i][kk] = f2bf(f[i] * scl);
    }
    __syncthreads();

    f32x4 acc = {};
    #pragma unroll
    for (int i = 0; i < 8; ++i) {
        const int cur = i & 1;
        bf16x8 ca0 = a0, ca1 = a1;
        if (i < 7) {
            const int k0 = (i + 1) * 64;
            const float* sp = S + (k0 + kk) * 256 + c0 + 16 * dg;
            sv0 = *(const float4*)sp;      sv1 = *(const float4*)(sp + 4);
            sv2 = *(const float4*)(sp + 8); sv3 = *(const float4*)(sp + 12);
            a0 = *(const bf16x8*)(Ab + mrow * 512 + k0 + 8 * quad);
            a1 = *(const bf16x8*)(Ab + mrow * 512 + k0 + 32 + 8 * quad);
        }
        {
            bf16x8 b0 = *(bf16x8*)&Bs[cur][wc + mrow][8 * quad];
            bf16x8 b1 = *(bf16x8*)&Bs[cur][wc + mrow][32 + 8 * quad];
            acc = __builtin_amdgcn_mfma_f32_16x16x32_bf16(ca0, b0, acc, 0, 0, 0);
            acc = __builtin_amdgcn_mfma_f32_16x16x32_bf16(ca1, b1, acc, 0, 0, 0);
        }
        if (i < 7) {
            const int k0 = (i + 1) * 64;
            const float scl = which ? rinv_s[k0 + kk] : 1.f;
            const float f[16] = { sv0.x, sv0.y, sv0.z, sv0.w, sv1.x, sv1.y, sv1.z, sv1.w,
                                  sv2.x, sv2.y, sv2.z, sv2.w, sv3.x, sv3.y, sv3.z, sv3.w };
            #pragma unroll
            for (int u = 0; u < 16; ++u) Bs[cur ^ 1][16 * dg + u][kk] = f2bf(f[u] * scl);
        }
        __syncthreads();
    }

    const int col = c0 + wc + mrow;
    #pragma unroll
    for (int reg = 0; reg < 4; ++reg) {
        const int row = quad * 4 + reg;
        const float scale = which ? hv : hv * rinv_s[row];
        out[row * 256 + col] = fmaf(scale, acc[reg], base[row * 256 + col]);
    }
}

// ---------------------------------------------------------------------------
extern "C" void kernel_launch(void* const* d_in, const int* in_sizes, int n_in,
                              void* d_out, int out_size, void* d_ws, size_t ws_size,
                              hipStream_t stream)
{
    const float* vis = (const float*)d_in[0];
    const float* txt = (const float*)d_in[1];
    const float* Wv  = (const float*)d_in[2];
    const float* bv  = (const float*)d_in[3];
    const float* Wt  = (const float*)d_in[4];
    const float* bt  = (const float*)d_in[5];
    const float* h   = (const float*)d_in[6];

    float* outv = (float*)d_out;                  // 2*512*256
    float* outt = (float*)d_out + 2 * 512 * 256;

    short* expq = (short*)d_ws;                   // 2048 x 1024 bf16 (4 MB)
    short* E    = expq + 2048 * 1024;             // 1024 x 512 bf16 (1 MB)
    short* ET   = E + 1024 * 512;                 // 1024 x 512 bf16 (1 MB)
    float* rs   = (float*)(ET + 1024 * 512);      // 1024 x 32 fp32 (128 KB)

    proj_expand_kernel<<<dim3(64, 4, 2), 256, 0, stream>>>(vis, txt, Wv, bv, Wt, bt, expq);
    logits_kernel<<<dim3(32, 8, 2), 256, 0, stream>>>(expq, E, ET, rs);
    out_kernel<<<dim3(32, 4, 4), 256, 0, stream>>>(vis, txt, E, ET, rs, h, outv, outt);
}